// Round 12
// baseline (156.994 us; speedup 1.0000x reference)
//
#include <hip/hip_runtime.h>
#include <hip/hip_bf16.h>

// CriticREM: out = relu(relu([state|action]W1^T+b1)W2^T+b2) @ Wc^T + bc
//   Wc = sum_h alpha_h * Wh[h], bc = sum_h alpha_h * bh[h]
// B=65536, IN=128, HID=256, NUM_HEADS=200, OUT=1
//
// R12: R11's single-dispatch straightline body with DOUBLE tile (BM=128,
//   NTILES=2): barriers/block 12 -> 6, phases 2x longer (better intra-phase
//   wave overlap, half the block-wide drain events). Dynamic LDS ~105KB via
//   hipFuncSetAttribute (proven in R8). Weight frags pinned per scalar
//   component (R11 fix) so they stay register-resident (R5/R8 sink hazard).
//   px prefetch issued post-B barrier, consumed at next staging (short
//   liveness; hidden under GEMM2's 128 MFMAs).

#define B_TOTAL 65536
#define SDIM 96
#define ADIM 32
#define IN_F 128
#define HID 256
#define NHEADS 200
#define BM 128          // batch rows per tile
#define NTILES 2        // tiles per block (grid 256 = 1 block/CU)
#define XS_PITCH 132    // 66 dw row stride == 2 mod 32: conflict-free class (R2)
#define H1_PITCH 260    // 130 dw == 2 mod 32: measured 0 conflicts (R2)
#define XS_BYTES (BM * XS_PITCH * 2)              // 33792
#define H1_BYTES (BM * H1_PITCH * 2)              // 66560
#define SP_BYTES (8 * BM * 4)                     // 4096
#define WCP_BYTES (2 * HID * 4)                   // 2048
#define WC_BYTES ((HID + 1) * 4)                  // 1028
#define SMEM_BYTES (XS_BYTES + H1_BYTES + SP_BYTES + WCP_BYTES + WC_BYTES)

typedef __bf16 bf16;
typedef __attribute__((ext_vector_type(4))) __bf16 bf16x4;
typedef __attribute__((ext_vector_type(8))) __bf16 bf16x8;
typedef __attribute__((ext_vector_type(4))) float f32x4;

static __device__ __forceinline__ float4 pack_bf16x8_as_f4(float4 a, float4 b) {
    union { bf16x8 h; float4 f; } u;
    u.h = (bf16x8){(bf16)a.x, (bf16)a.y, (bf16)a.z, (bf16)a.w,
                   (bf16)b.x, (bf16)b.y, (bf16)b.z, (bf16)b.w};
    return u.f;
}
static __device__ __forceinline__ bf16x8 as_bf16x8(float4 v) {
    union { float4 f; bf16x8 h; } u;
    u.f = v;
    return u.h;
}
static __device__ __forceinline__ void pin_f4(float4& v) {
    asm volatile("" : "+v"(v.x), "+v"(v.y), "+v"(v.z), "+v"(v.w));
}

// ---- single fused kernel: 512 threads (8 waves), 2 tiles of 128 rows ----
__global__ __launch_bounds__(512, 2) void critic_kernel(
        const float* __restrict__ state, const float* __restrict__ action,
        const float* __restrict__ alphas,
        const float* __restrict__ W1, const float* __restrict__ b1,
        const float* __restrict__ W2, const float* __restrict__ b2,
        const float* __restrict__ Wh, const float* __restrict__ bh,
        float* __restrict__ out) {

    extern __shared__ char smem[];
    bf16*  xs    = (bf16*)smem;                                  // [BM][XS_PITCH]
    bf16*  h1s   = (bf16*)(smem + XS_BYTES);                     // [BM][H1_PITCH]
    float* sPart = (float*)(smem + XS_BYTES + H1_BYTES);         // [8][BM]
    float* sWcP  = (float*)(smem + XS_BYTES + H1_BYTES + SP_BYTES);          // [2][HID]
    float* sWc   = (float*)(smem + XS_BYTES + H1_BYTES + SP_BYTES + WCP_BYTES); // [HID+1]

    const int tid  = threadIdx.x;
    const int wave = tid >> 6;      // 0..7
    const int lane = tid & 63;
    const int q    = lane >> 4;     // 0..3
    const int ln   = lane & 15;     // 0..15
    const int colw = wave * 32;     // this wave's 32-hidden-col slice
    const int brow0 = blockIdx.x * (BM * NTILES);

    // ---- preamble: weight fragments from fp32 W1/W2, converted + PINNED ----
    float4 w1s[4][2];   // 32 VGPR (bf16x8 stored as float4)
    #pragma unroll
    for (int ks = 0; ks < 4; ++ks)
        #pragma unroll
        for (int nt = 0; nt < 2; ++nt) {
            const float* p = W1 + (size_t)(colw + nt * 16 + ln) * IN_F + ks * 32 + q * 8;
            w1s[ks][nt] = pack_bf16x8_as_f4(((const float4*)p)[0], ((const float4*)p)[1]);
        }
    float4 w2s[8][2];   // 64 VGPR
    #pragma unroll
    for (int ks = 0; ks < 8; ++ks)
        #pragma unroll
        for (int nt = 0; nt < 2; ++nt) {
            const float* p = W2 + (size_t)(colw + nt * 16 + ln) * HID + ks * 32 + q * 8;
            w2s[ks][nt] = pack_bf16x8_as_f4(((const float4*)p)[0], ((const float4*)p)[1]);
        }
    #pragma unroll
    for (int ks = 0; ks < 4; ++ks)
        #pragma unroll
        for (int nt = 0; nt < 2; ++nt)
            pin_f4(w1s[ks][nt]);
    #pragma unroll
    for (int ks = 0; ks < 8; ++ks)
        #pragma unroll
        for (int nt = 0; nt < 2; ++nt)
            pin_f4(w2s[ks][nt]);

    // bias constants: hidden col n = colw + nt*16 + q*4 + r -> float4 loads
    f32x4 b1v[2], b2v[2];
    #pragma unroll
    for (int nt = 0; nt < 2; ++nt) {
        const int n4 = colw + nt * 16 + q * 4;
        b1v[nt] = *(const f32x4*)&b1[n4];
        b2v[nt] = *(const f32x4*)&b2[n4];
    }

    // ---- Wc collapse: thread (half, c) sums 100 heads for col c ----
    {
        const int c    = tid & 255;
        const int half = tid >> 8;
        float p = 0.f;
        #pragma unroll 10
        for (int i = 0; i < 100; ++i) {
            const int h = half * 100 + i;
            p += alphas[h] * Wh[(size_t)h * HID + c];
        }
        sWcP[half * HID + c] = p;
    }
    // bc: wave 0 shfl-reduce over 200 heads
    if (tid < 64) {
        float p = 0.f;
        #pragma unroll
        for (int i = 0; i < 4; ++i) {
            const int h = tid + i * 64;
            if (h < NHEADS) p += alphas[h] * bh[h];
        }
        #pragma unroll
        for (int off = 1; off < 64; off <<= 1)
            p += __shfl_xor(p, off, 64);
        if (tid == 0) sWc[HID] = p;
    }

    // x staging geometry: 512 threads x 4 chunks of 8 fp32 (128 rows x 16 chunks)
    // chunk c = tid + i*512: r = c>>4, c8 = c&15
    float4 px[4][2];
    #pragma unroll
    for (int i = 0; i < 4; ++i) {
        const int c  = tid + i * 512;
        const int r  = c >> 4;
        const int c8 = c & 15;
        const float* s = (c8 < 12) ? (state  + (size_t)(brow0 + r) * SDIM + c8 * 8)
                                   : (action + (size_t)(brow0 + r) * ADIM + (c8 - 12) * 8);
        px[i][0] = ((const float4*)s)[0];
        px[i][1] = ((const float4*)s)[1];
    }

    for (int t = 0; t < NTILES; ++t) {
        const int row0 = brow0 + t * BM;

        // stage x tile from px regs
        #pragma unroll
        for (int i = 0; i < 4; ++i) {
            const int c  = tid + i * 512;
            const int r  = c >> 4;
            const int c8 = c & 15;
            *(bf16x8*)&xs[r * XS_PITCH + c8 * 8] =
                (bf16x8){(bf16)px[i][0].x, (bf16)px[i][0].y, (bf16)px[i][0].z, (bf16)px[i][0].w,
                         (bf16)px[i][1].x, (bf16)px[i][1].y, (bf16)px[i][1].z, (bf16)px[i][1].w};
        }
        __syncthreads();   // A(t): xs visible (t==0: also sWcP/bc visible)

        // one-time: combine Wc partials (ordered before first wcv use by B(t))
        if (t == 0 && tid < HID)
            sWc[tid] = sWcP[tid] + sWcP[HID + tid];

        // ---- GEMM1(t): D1[n][m] = W1 . x^T ; epi1 -> h1s ----
        f32x4 acc[8][2];
        #pragma unroll
        for (int mt = 0; mt < 8; ++mt)
            #pragma unroll
            for (int nt = 0; nt < 2; ++nt)
                acc[mt][nt] = (f32x4){0.f, 0.f, 0.f, 0.f};

        #pragma unroll
        for (int ks = 0; ks < 4; ++ks) {
            const int k0 = ks * 32 + q * 8;
            bf16x8 bfr[8];
            #pragma unroll
            for (int mt = 0; mt < 8; ++mt)
                bfr[mt] = *(const bf16x8*)&xs[(mt * 16 + ln) * XS_PITCH + k0];
            #pragma unroll
            for (int mt = 0; mt < 8; ++mt)
                #pragma unroll
                for (int nt = 0; nt < 2; ++nt)
                    acc[mt][nt] = __builtin_amdgcn_mfma_f32_16x16x32_bf16(
                        as_bf16x8(w1s[ks][nt]), bfr[mt], acc[mt][nt], 0, 0, 0);
        }
        #pragma unroll
        for (int nt = 0; nt < 2; ++nt)
            #pragma unroll
            for (int mt = 0; mt < 8; ++mt) {
                bf16x4 v4;
                #pragma unroll
                for (int r = 0; r < 4; ++r) {
                    float v = acc[mt][nt][r] + b1v[nt][r];
                    v = v > 0.f ? v : 0.f;
                    v4[r] = (bf16)v;
                }
                *(bf16x4*)&h1s[(mt * 16 + ln) * H1_PITCH + colw + nt * 16 + q * 4] = v4;
            }
        __syncthreads();   // B(t): h1s visible, sWc visible

        // issue next tile's x loads (hidden under GEMM2's 128 MFMAs)
        if (t + 1 < NTILES) {
            const int n0 = brow0 + (t + 1) * BM;
            #pragma unroll
            for (int i = 0; i < 4; ++i) {
                const int c  = tid + i * 512;
                const int r  = c >> 4;
                const int c8 = c & 15;
                const float* s = (c8 < 12) ? (state  + (size_t)(n0 + r) * SDIM + c8 * 8)
                                           : (action + (size_t)(n0 + r) * ADIM + (c8 - 12) * 8);
                px[i][0] = ((const float4*)s)[0];
                px[i][1] = ((const float4*)s)[1];
            }
        }

        // ---- GEMM2(t): D2[n][m] = W2 . h1^T ; epi2 -> sPart ----
        #pragma unroll
        for (int mt = 0; mt < 8; ++mt)
            #pragma unroll
            for (int nt = 0; nt < 2; ++nt)
                acc[mt][nt] = (f32x4){0.f, 0.f, 0.f, 0.f};

        #pragma unroll
        for (int ks = 0; ks < 8; ++ks) {
            const int k0 = ks * 32 + q * 8;
            bf16x8 bfr[8];
            #pragma unroll
            for (int mt = 0; mt < 8; ++mt)
                bfr[mt] = *(const bf16x8*)&h1s[(mt * 16 + ln) * H1_PITCH + k0];
            #pragma unroll
            for (int mt = 0; mt < 8; ++mt)
                #pragma unroll
                for (int nt = 0; nt < 2; ++nt)
                    acc[mt][nt] = __builtin_amdgcn_mfma_f32_16x16x32_bf16(
                        as_bf16x8(w2s[ks][nt]), bfr[mt], acc[mt][nt], 0, 0, 0);
        }

        // epi2: bias+relu+Wc-dot in-lane; cross-lane reduce over q only
        f32x4 wcv[2];
        #pragma unroll
        for (int nt = 0; nt < 2; ++nt)
            wcv[nt] = *(const f32x4*)&sWc[colw + nt * 16 + q * 4];

        float partial[8];
        #pragma unroll
        for (int mt = 0; mt < 8; ++mt) {
            float p = 0.f;
            #pragma unroll
            for (int nt = 0; nt < 2; ++nt)
                #pragma unroll
                for (int r = 0; r < 4; ++r) {
                    float v = acc[mt][nt][r] + b2v[nt][r];
                    v = v > 0.f ? v : 0.f;
                    p += v * wcv[nt][r];
                }
            partial[mt] = p;
        }
        #pragma unroll
        for (int mt = 0; mt < 8; ++mt) {
            partial[mt] += __shfl_xor(partial[mt], 16, 64);
            partial[mt] += __shfl_xor(partial[mt], 32, 64);
        }
        if (q == 0) {
            #pragma unroll
            for (int mt = 0; mt < 8; ++mt)
                sPart[wave * BM + mt * 16 + ln] = partial[mt];
        }
        __syncthreads();   // C(t): sPart visible; next tile may overwrite xs/h1s

        if (tid < BM) {
            float v = sWc[HID];
            #pragma unroll
            for (int w = 0; w < 8; ++w) v += sPart[w * BM + tid];
            out[row0 + tid] = v;
        }
    }
}

extern "C" void kernel_launch(void* const* d_in, const int* in_sizes, int n_in,
                              void* d_out, int out_size, void* d_ws, size_t ws_size,
                              hipStream_t stream) {
    const float* state  = (const float*)d_in[0];
    const float* action = (const float*)d_in[1];
    const float* alphas = (const float*)d_in[2];
    const float* W1     = (const float*)d_in[3];
    const float* b1     = (const float*)d_in[4];
    const float* W2     = (const float*)d_in[5];
    const float* b2     = (const float*)d_in[6];
    const float* Wh     = (const float*)d_in[7];
    const float* bh     = (const float*)d_in[8];
    float* out = (float*)d_out;

    // allow >64KB dynamic LDS (host-side module state; idempotent; graph-safe)
    (void)hipFuncSetAttribute((const void*)critic_kernel,
                              hipFuncAttributeMaxDynamicSharedMemorySize,
                              SMEM_BYTES);

    critic_kernel<<<B_TOTAL / (BM * NTILES), 512, SMEM_BYTES, stream>>>(
        state, action, alphas, W1, b1, W2, b2, Wh, bh, out);
}